// Round 5
// baseline (909.638 us; speedup 1.0000x reference)
//
#include <hip/hip_runtime.h>
#include <math.h>

#define NQ  4096      // queries
#define MB  100000    // bank rows
#define DD  512       // dim
#define QT  128       // query tile (C cols)
#define BT  128       // bank tile  (C rows)
#define BK  32        // K step
#define KIT (DD / BK) // 16
#define NCH ((MB + BT - 1) / BT)  // 782 chunks
#define NWG (32 * NCH)            // 25024 blocks = 8 * 3128
#define MARGIN 6e-3f
#define RQ  64        // queries per reduce block

typedef __attribute__((ext_vector_type(8))) short short8;
typedef __attribute__((ext_vector_type(4))) float f32x4;

__device__ inline unsigned int umax32(unsigned int a, unsigned int b) { return a > b ? a : b; }
__device__ inline unsigned int umin32(unsigned int a, unsigned int b) { return a < b ? a : b; }

// fp32 -> bf16 bits, round-to-nearest-even
__device__ inline unsigned short f2bf(float f) {
  unsigned int u = __float_as_uint(f);
  u += 0x7FFFu + ((u >> 16) & 1u);
  return (unsigned short)(u >> 16);
}

// async global->LDS, 16B per lane. LDS dest must be wave-uniform-base + lane*16.
__device__ inline void gload_lds16(const void* g, void* l) {
  __builtin_amdgcn_global_load_lds(
      (const __attribute__((address_space(1))) unsigned int*)g,
      (__attribute__((address_space(3))) unsigned int*)l, 16, 0, 0);
}

// ---- kernel 1: L2-normalize rows and cast to bf16 -------------------------
__global__ __launch_bounds__(256) void nrm_cast(const float* __restrict__ qin,
                                                const float* __restrict__ bin,
                                                unsigned short* __restrict__ qb,
                                                unsigned short* __restrict__ bb) {
  int wave = threadIdx.x >> 6, lane = threadIdx.x & 63;
  int row = blockIdx.x * 4 + wave;
  const float* src;
  unsigned short* dst;
  if (row < NQ) {
    src = qin + (size_t)row * DD;
    dst = qb + (size_t)row * DD;
  } else {
    int r2 = row - NQ;
    if (r2 >= MB) return;
    src = bin + (size_t)r2 * DD;
    dst = bb + (size_t)r2 * DD;
  }
  const float4* s4 = (const float4*)src;
  float4 x0 = s4[lane * 2], x1 = s4[lane * 2 + 1];
  float ss = x0.x * x0.x + x0.y * x0.y + x0.z * x0.z + x0.w * x0.w +
             x1.x * x1.x + x1.y * x1.y + x1.z * x1.z + x1.w * x1.w;
  #pragma unroll
  for (int m = 1; m < 64; m <<= 1) ss += __shfl_xor(ss, m, 64);
  float r = 1.0f / fmaxf(sqrtf(ss), 1e-12f);
  short8 v;
  v[0] = (short)f2bf(x0.x * r); v[1] = (short)f2bf(x0.y * r);
  v[2] = (short)f2bf(x0.z * r); v[3] = (short)f2bf(x0.w * r);
  v[4] = (short)f2bf(x1.x * r); v[5] = (short)f2bf(x1.y * r);
  v[6] = (short)f2bf(x1.z * r); v[7] = (short)f2bf(x1.w * r);
  *(short8*)(dst + (size_t)lane * 8) = v;
}

// ---- kernel 2: transposed bf16 MFMA GEMM (C = bank x query) + packed top2 -
// T4 counted-vmcnt pipeline: STAGE(kt+1) stays in flight across the phase
// barrier (s_waitcnt vmcnt(4) = 4 newest outstanding allowed); each wave
// waits its own count, s_barrier makes the buffer collectively ready.
__global__ __launch_bounds__(256, 3) void gemm_top2(
    const unsigned short* __restrict__ qb,
    const unsigned short* __restrict__ bb,
    uint2* __restrict__ cand) {
  __shared__ unsigned short sM[2][BT * BK];  // bank tiles (dbuf) 2x8KB
  __shared__ unsigned short sN[2][QT * BK];  // query tiles (dbuf) 2x8KB
  __shared__ unsigned int rowwin[QT][2][2];  // [qcol][bank-half][k1,k2]  2KB

  int tid = threadIdx.x;
  int wave = tid >> 6, lane = tid & 63;

  // XCD-aware swizzle: 25024 = 8 * 3128, bijective
  int w = blockIdx.x;
  int sw = (w & 7) * (NWG / 8) + (w >> 3);
  int bx = sw & 31;       // q-tile 0..31
  int by = sw >> 5;       // bank chunk 0..781
  int q0 = bx * QT, c0 = by * BT;
  int wm = (wave >> 1) * 64;  // bank-row half of this wave
  int wn = (wave & 1) * 64;   // q-col half of this wave

  f32x4 acc[4][4];
  #pragma unroll
  for (int i = 0; i < 4; ++i)
    #pragma unroll
    for (int j = 0; j < 4; ++j) acc[i][j] = (f32x4){0.f, 0.f, 0.f, 0.f};

  // staging decomposition (validated round-2/4 form)
  int sr = tid >> 2;             // row within 64-row half
  int slot = tid & 3;            // 16B slot within row
  int swz = (tid >> 4) & 3;      // (sr>>2)&3
  int ce = (slot ^ swz) * 8;     // swizzled global chunk offset (elements)
  int br0 = c0 + sr;       if (br0 >= MB) br0 = MB - 1;
  int br1 = c0 + 64 + sr;  if (br1 >= MB) br1 = MB - 1;

  // fragment read decomposition
  int rr = lane & 15;
  int ck = lane >> 4;
  int rco = (ck ^ ((rr >> 2) & 3)) * 8;

  const unsigned short* gM0 = bb + (size_t)br0 * DD + ce;
  const unsigned short* gM1 = bb + (size_t)br1 * DD + ce;
  const unsigned short* gN0 = qb + (size_t)(q0 + sr) * DD + ce;
  const unsigned short* gN1 = qb + (size_t)(q0 + 64 + sr) * DD + ce;

  auto STAGE = [&](int kt, int buf) {
    int kk = kt * BK;
    gload_lds16(gM0 + kk, &sM[buf][tid * 8]);
    gload_lds16(gM1 + kk, &sM[buf][2048 + tid * 8]);
    gload_lds16(gN0 + kk, &sN[buf][tid * 8]);
    gload_lds16(gN1 + kk, &sN[buf][2048 + tid * 8]);
  };

  auto COMPUTE = [&](int buf) {
    const unsigned short* M0 = sM[buf];
    const unsigned short* N0 = sN[buf];
    short8 af[4], bg[4];
    #pragma unroll
    for (int mi = 0; mi < 4; ++mi)
      af[mi] = *(const short8*)&M0[(wm + mi * 16 + rr) * BK + rco];
    #pragma unroll
    for (int ni = 0; ni < 4; ++ni)
      bg[ni] = *(const short8*)&N0[(wn + ni * 16 + rr) * BK + rco];
    #pragma unroll
    for (int mi = 0; mi < 4; ++mi)
      #pragma unroll
      for (int ni = 0; ni < 4; ++ni)
        acc[mi][ni] = __builtin_amdgcn_mfma_f32_16x16x32_bf16(af[mi], bg[ni],
                                                              acc[mi][ni], 0, 0, 0);
  };

  STAGE(0, 0);
  for (int kt = 0; kt < KIT - 1; ++kt) {
    STAGE(kt + 1, (kt & 1) ^ 1);             // 4 newest loads -> next buf
    asm volatile("s_waitcnt vmcnt(4)" ::: "memory");  // current buf complete
    __builtin_amdgcn_s_barrier();
    __builtin_amdgcn_sched_barrier(0);       // pin: no ds_read hoists above
    COMPUTE(kt & 1);
    __builtin_amdgcn_sched_barrier(0);       // pin: nothing sinks below
    __builtin_amdgcn_s_barrier();            // raw: no vmcnt drain
  }
  // peeled last iteration: nothing else in flight -> drain
  asm volatile("s_waitcnt vmcnt(0)" ::: "memory");
  __builtin_amdgcn_s_barrier();
  __builtin_amdgcn_sched_barrier(0);
  COMPUTE((KIT - 1) & 1);

  // ---- epilogue: packed-key top2 per query col over 128 bank rows ---------
  // key u32 = (f32bits & ~127) | (127 - row_in_chunk); order-preserving for
  // positive sims; ties break toward smaller bank row; negatives masked to 0.
  // C layout: col = lane&15 (+ni*16+wn), row = (lane>>4)*4 + reg (+mi*16+wm)
  int g = lane >> 4, cl = lane & 15;
  bool tail = (c0 + BT > MB);
  int nb = 127 - wm - g * 4;
  unsigned int K1[4], K2[4];
  #pragma unroll
  for (int ni = 0; ni < 4; ++ni) { K1[ni] = 0u; K2[ni] = 0u; }

  #pragma unroll
  for (int mi = 0; mi < 4; ++mi) {
    #pragma unroll
    for (int r2 = 0; r2 < 4; ++r2) {
      int rowoff = mi * 16 + r2;
      #pragma unroll
      for (int ni = 0; ni < 4; ++ni) {
        float v = acc[mi][ni][r2];
        unsigned int key = (__float_as_uint(v) & 0xFFFFFF80u) |
                           (unsigned int)(nb - rowoff);
        bool ok = v > 0.0f;
        if (tail) ok = ok && (c0 + wm + g * 4 + rowoff < MB);
        key = ok ? key : 0u;
        unsigned int mx = umax32(K1[ni], key), mn = umin32(K1[ni], key);
        K1[ni] = mx;
        K2[ni] = umax32(K2[ni], mn);
      }
    }
  }

  #pragma unroll
  for (int m = 16; m <= 32; m <<= 1) {
    #pragma unroll
    for (int ni = 0; ni < 4; ++ni) {
      unsigned int o1 = (unsigned int)__shfl_xor((int)K1[ni], m, 64);
      unsigned int o2 = (unsigned int)__shfl_xor((int)K2[ni], m, 64);
      unsigned int mx = umax32(K1[ni], o1), mn = umin32(K1[ni], o1);
      K1[ni] = mx;
      K2[ni] = umax32(mn, umax32(K2[ni], o2));
    }
  }
  if (g == 0) {
    #pragma unroll
    for (int ni = 0; ni < 4; ++ni) {
      int qc = wn + ni * 16 + cl;
      rowwin[qc][wave >> 1][0] = K1[ni];
      rowwin[qc][wave >> 1][1] = K2[ni];
    }
  }
  __syncthreads();

  if (tid < QT) {
    unsigned int a1 = rowwin[tid][0][0], a2 = rowwin[tid][0][1];
    unsigned int b1 = rowwin[tid][1][0], b2 = rowwin[tid][1][1];
    unsigned int k1 = umax32(a1, b1);
    unsigned int k2 = umax32(umin32(a1, b1), umax32(a2, b2));
    cand[(size_t)by * NQ + q0 + tid] = make_uint2(k1, k2);
  }
}

// ---- kernel 3: query-blocked candidate select + exact fp32 refine ---------
// 64 blocks x 64 queries; lane <-> query, wave <-> chunk stripe (c = w mod 4)
// so cand reads are contiguous 512B per wave (one fetch per line).
__global__ __launch_bounds__(256) void reduce_refine(
    const float* __restrict__ qraw, const float* __restrict__ braw,
    const int* __restrict__ cat, const int* __restrict__ shp,
    const uint2* __restrict__ cand, int* __restrict__ out) {
  int tid = threadIdx.x, wave = tid >> 6, lane = tid & 63;
  int q0 = blockIdx.x * RQ;
  int q = q0 + lane;

  __shared__ unsigned int wm[4][RQ];
  __shared__ int cnt[RQ];
  __shared__ int sel[RQ][16];
  __shared__ float rvv[RQ][16];
  __shared__ unsigned short queue[RQ * 16];
  __shared__ int qn;

  // pass 1: per-lane max of its query's chunk-max keys over this wave's stripe
  unsigned int mk = 0;
  for (int c = wave; c < NCH; c += 4)
    mk = umax32(mk, cand[(size_t)c * NQ + q].x);
  wm[wave][lane] = mk;
  if (wave == 0) cnt[lane] = 0;
  __syncthreads();
  unsigned int M1 = umax32(umax32(wm[0][lane], wm[1][lane]),
                           umax32(wm[2][lane], wm[3][lane]));
  float thr = __uint_as_float(M1 & 0xFFFFFF80u) - MARGIN;

  // pass 2: select candidates within margin (reads now L2-hot)
  for (int c = wave; c < NCH; c += 4) {
    uint2 e = cand[(size_t)c * NQ + q];
    float f1 = __uint_as_float(e.x & 0xFFFFFF80u);
    float f2 = __uint_as_float(e.y & 0xFFFFFF80u);
    if (f1 >= thr) {
      int p = atomicAdd(&cnt[lane], 1);
      if (p < 16) sel[lane][p] = c * BT + 127 - (int)(e.x & 127u);
    }
    if (f2 >= thr) {
      int p = atomicAdd(&cnt[lane], 1);
      if (p < 16) sel[lane][p] = c * BT + 127 - (int)(e.y & 127u);
    }
  }
  __syncthreads();

  // flatten to a work queue (serial; ~100 entries typical)
  if (tid == 0) {
    int t = 0;
    for (int i = 0; i < RQ; ++i) {
      int n = cnt[i] < 16 ? cnt[i] : 16;
      for (int s = 0; s < n; ++s) queue[t++] = (unsigned short)((i << 4) | s);
    }
    qn = t;
  }
  __syncthreads();

  // exact fp32 refine, one candidate per wave
  int total = qn;
  for (int e = wave; e < total; e += 4) {
    int ql = queue[e] >> 4, sl = queue[e] & 15;
    int bi = sel[ql][sl];
    const float4* q4 = (const float4*)(qraw + (size_t)(q0 + ql) * DD);
    const float4* b4 = (const float4*)(braw + (size_t)bi * DD);
    float4 qa = q4[lane * 2], qv = q4[lane * 2 + 1];
    float4 ba = b4[lane * 2], bv = b4[lane * 2 + 1];
    float dot = qa.x * ba.x + qa.y * ba.y + qa.z * ba.z + qa.w * ba.w +
                qv.x * bv.x + qv.y * bv.y + qv.z * bv.z + qv.w * bv.w;
    float qss = qa.x * qa.x + qa.y * qa.y + qa.z * qa.z + qa.w * qa.w +
                qv.x * qv.x + qv.y * qv.y + qv.z * qv.z + qv.w * qv.w;
    float bss = ba.x * ba.x + ba.y * ba.y + ba.z * ba.z + ba.w * ba.w +
                bv.x * bv.x + bv.y * bv.y + bv.z * bv.z + bv.w * bv.w;
    #pragma unroll
    for (int m = 1; m < 64; m <<= 1) {
      dot += __shfl_xor(dot, m, 64);
      qss += __shfl_xor(qss, m, 64);
      bss += __shfl_xor(bss, m, 64);
    }
    if (lane == 0) {
      float qn_ = fmaxf(sqrtf(qss), 1e-12f);
      float bn_ = fmaxf(sqrtf(bss), 1e-12f);
      rvv[ql][sl] = dot / (qn_ * bn_);
    }
  }
  __syncthreads();

  // final argmax per query (smallest-index tie-break, matches numpy)
  if (wave == 0) {
    int n = cnt[lane] < 16 ? cnt[lane] : 16;
    float bv = rvv[lane][0];
    int bidx = sel[lane][0];
    for (int s = 1; s < n; ++s) {
      float v = rvv[lane][s];
      int ix = sel[lane][s];
      if (v > bv || (v == bv && ix < bidx)) { bv = v; bidx = ix; }
    }
    out[q] = cat[bidx];
    out[NQ + q] = shp[bidx];
  }
}

// ---- launch ---------------------------------------------------------------
extern "C" void kernel_launch(void* const* d_in, const int* in_sizes, int n_in,
                              void* d_out, int out_size, void* d_ws, size_t ws_size,
                              hipStream_t stream) {
  const float* qin = (const float*)d_in[0];
  const float* bin = (const float*)d_in[1];
  const int* cat = (const int*)d_in[2];
  const int* shp = (const int*)d_in[3];
  int* out = (int*)d_out;

  char* ws = (char*)d_ws;
  unsigned short* qb = (unsigned short*)ws;
  unsigned short* bb = (unsigned short*)(ws + (size_t)NQ * DD * 2);
  uint2* cand = (uint2*)(ws + (size_t)NQ * DD * 2 + (size_t)MB * DD * 2);
  // ws: 4 MB (qb) + 102.4 MB (bb) + 25.6 MB (cand) = 132 MB

  nrm_cast<<<(NQ + MB) / 4, 256, 0, stream>>>(qin, bin, qb, bb);
  gemm_top2<<<NWG, 256, 0, stream>>>(qb, bb, cand);
  reduce_refine<<<NQ / RQ, 256, 0, stream>>>(qin, bin, cat, shp, cand, out);
}